// Round 1
// baseline (20499.504 us; speedup 1.0000x reference)
//
#include <hip/hip_runtime.h>
#include <hip/hip_bf16.h>
#include <math.h>

namespace {

constexpr int Bsz = 2;
constexpr int T_IN = 8192;
constexpr int C1 = 1024, L1 = 2048;
constexpr int C2 = 2048, L2 = 512;
constexpr int C3 = 4096, LS = 255;
constexpr int DINNER = 8192;
constexpr int DSTATE = 16;
constexpr int DTRANK = 256;
constexpr int NX = DTRANK + 2 * DSTATE;   // 288
constexpr int MROWS = Bsz * LS;           // 510

__device__ __forceinline__ float silu_f(float x) { return x / (1.f + __expf(-x)); }

// ---------------- encoder conv1: [B,1,8192] -> [B,1024,2048], s=4 p=2 k=8, +BN+ReLU
__global__ __launch_bounds__(256) void k_conv1(
    const float* __restrict__ x, const float* __restrict__ w,
    const float* __restrict__ bias, const float* __restrict__ g,
    const float* __restrict__ be, const float* __restrict__ rm,
    const float* __restrict__ rv, float* __restrict__ out)
{
    int idx = blockIdx.x * 256 + threadIdx.x;   // B*C1*L1
    int l = idx % L1;
    int c = (idx / L1) % C1;
    int b = idx / (L1 * C1);
    int start = l * 4 - 2;
    float acc = 0.f;
#pragma unroll
    for (int k = 0; k < 8; ++k) {
        int t = start + k;
        if (t >= 0 && t < T_IN) acc += (x[b * T_IN + t] + 1.f) * w[c * 8 + k];
    }
    acc += bias[c];
    float s = g[c] * rsqrtf(rv[c] + 1e-5f);
    float o = (acc - rm[c]) * s + be[c];
    out[idx] = fmaxf(o, 0.f);
}

// ---------------- encoder conv2: [B,1024,2048] -> [B,2048,512], s=4 p=2 k=8, +BN+ReLU
__global__ __launch_bounds__(512) void k_conv2(
    const float* __restrict__ in, const float* __restrict__ w,
    const float* __restrict__ bias, const float* __restrict__ g,
    const float* __restrict__ be, const float* __restrict__ rm,
    const float* __restrict__ rv, float* __restrict__ out)
{
    __shared__ float ws[C1 * 8];   // 32 KB
    int oc = blockIdx.x % C2, b = blockIdx.x / C2;
    int tid = threadIdx.x;
    for (int i = tid; i < C1 * 8; i += 512) ws[i] = w[(size_t)oc * C1 * 8 + i];
    __syncthreads();
    int l = tid, start = l * 4 - 2;
    float acc = 0.f;
    const float* ib = in + (size_t)b * C1 * L1;
    if (l > 0 && l < L2 - 1) {
        for (int ic = 0; ic < C1; ++ic) {
            const float* ip = ib + ic * L1 + start;
            const float* wp = ws + ic * 8;
#pragma unroll
            for (int k = 0; k < 8; ++k) acc += ip[k] * wp[k];
        }
    } else {
        for (int ic = 0; ic < C1; ++ic) {
            const float* ip = ib + ic * L1;
            const float* wp = ws + ic * 8;
#pragma unroll
            for (int k = 0; k < 8; ++k) { int t = start + k; if (t >= 0 && t < L1) acc += ip[t] * wp[k]; }
        }
    }
    acc += bias[oc];
    float s = g[oc] * rsqrtf(rv[oc] + 1e-5f);
    float o = (acc - rm[oc]) * s + be[oc];
    out[((size_t)b * C2 + oc) * L2 + l] = fmaxf(o, 0.f);
}

// ---------------- encoder conv3: [B,2048,512] -> h [B,255,4096] (transposed out), s=2 p=2 k=8, +BN+ReLU
__global__ __launch_bounds__(256) void k_conv3(
    const float* __restrict__ in, const float* __restrict__ w,
    const float* __restrict__ bias, const float* __restrict__ g,
    const float* __restrict__ be, const float* __restrict__ rm,
    const float* __restrict__ rv, float* __restrict__ hout)
{
    __shared__ float ws[512 * 8];  // 16 KB per chunk
    int oc = blockIdx.x % C3, b = blockIdx.x / C3;
    int l = threadIdx.x;           // 0..255, l<255 active
    int start = l * 2 - 2;
    float acc = 0.f;
    const float* ib = in + (size_t)b * C2 * L2;
    for (int ic0 = 0; ic0 < C2; ic0 += 512) {
        __syncthreads();
        for (int i = threadIdx.x; i < 512 * 8; i += 256) ws[i] = w[(size_t)oc * C2 * 8 + ic0 * 8 + i];
        __syncthreads();
        if (l < LS) {
            if (l > 0 && l < 254) {
                for (int icl = 0; icl < 512; ++icl) {
                    const float* ip = ib + (ic0 + icl) * L2 + start;
                    const float* wp = ws + icl * 8;
#pragma unroll
                    for (int k = 0; k < 8; ++k) acc += ip[k] * wp[k];
                }
            } else {
                for (int icl = 0; icl < 512; ++icl) {
                    const float* ip = ib + (ic0 + icl) * L2;
                    const float* wp = ws + icl * 8;
#pragma unroll
                    for (int k = 0; k < 8; ++k) { int t = start + k; if (t >= 0 && t < L2) acc += ip[t] * wp[k]; }
                }
            }
        }
    }
    if (l < LS) {
        acc += bias[oc];
        float s = g[oc] * rsqrtf(rv[oc] + 1e-5f);
        float o = (acc - rm[oc]) * s + be[oc];
        hout[((size_t)b * LS + l) * C3 + oc] = fmaxf(o, 0.f);
    }
}

// ---------------- RMSNorm over last dim 4096
__global__ __launch_bounds__(256) void k_rmsnorm(
    const float* __restrict__ h, const float* __restrict__ w, float* __restrict__ hs)
{
    int row = blockIdx.x;   // B*LS
    const float* xp = h + (size_t)row * C3;
    int tid = threadIdx.x;
    float ss = 0.f;
    for (int i = tid; i < C3; i += 256) { float v = xp[i]; ss += v * v; }
#pragma unroll
    for (int m = 32; m >= 1; m >>= 1) ss += __shfl_xor(ss, m, 64);
    __shared__ float red[4];
    if ((tid & 63) == 0) red[tid >> 6] = ss;
    __syncthreads();
    ss = red[0] + red[1] + red[2] + red[3];
    float sc = rsqrtf(ss / C3 + 1e-5f);
    for (int i = tid; i < C3; i += 256) hs[(size_t)row * C3 + i] = xp[i] * sc * w[i];
}

// ---------------- generic NT GEMM: C[m,n] = sum_k A[m*lda+k] * B[n*ldb+k]
// EPI 0: none, 1: +bias then softplus
template <int EPI>
__global__ __launch_bounds__(256) void k_gemm_nt(
    const float* __restrict__ A, int lda,
    const float* __restrict__ Bm, int ldb,
    float* __restrict__ C, int ldc,
    int M, int N, int K, const float* __restrict__ bias)
{
    __shared__ float As[64][17];
    __shared__ float Bs[64][17];
    int tx = threadIdx.x, ty = threadIdx.y;
    int t = ty * 16 + tx;
    int m0 = blockIdx.y * 64, n0 = blockIdx.x * 64;
    int lr = t >> 2;             // 0..63
    int lc = (t & 3) * 4;        // 0,4,8,12
    float acc[4][4] = {};
    for (int k0 = 0; k0 < K; k0 += 16) {
        float4 av = make_float4(0, 0, 0, 0), bv = make_float4(0, 0, 0, 0);
        int am = m0 + lr;
        if (am < M) av = *(const float4*)(A + (size_t)am * lda + k0 + lc);
        int bn = n0 + lr;
        if (bn < N) bv = *(const float4*)(Bm + (size_t)bn * ldb + k0 + lc);
        As[lr][lc] = av.x; As[lr][lc + 1] = av.y; As[lr][lc + 2] = av.z; As[lr][lc + 3] = av.w;
        Bs[lr][lc] = bv.x; Bs[lr][lc + 1] = bv.y; Bs[lr][lc + 2] = bv.z; Bs[lr][lc + 3] = bv.w;
        __syncthreads();
#pragma unroll
        for (int kk = 0; kk < 16; ++kk) {
            float a[4], b[4];
#pragma unroll
            for (int i = 0; i < 4; ++i) a[i] = As[ty * 4 + i][kk];
#pragma unroll
            for (int j = 0; j < 4; ++j) b[j] = Bs[tx * 4 + j][kk];
#pragma unroll
            for (int i = 0; i < 4; ++i)
#pragma unroll
                for (int j = 0; j < 4; ++j) acc[i][j] += a[i] * b[j];
        }
        __syncthreads();
    }
#pragma unroll
    for (int i = 0; i < 4; ++i) {
        int gm = m0 + ty * 4 + i;
        if (gm >= M) continue;
#pragma unroll
        for (int j = 0; j < 4; ++j) {
            int gn = n0 + tx * 4 + j;
            if (gn >= N) continue;
            float v = acc[i][j];
            if (EPI == 1) {
                v += bias[gn];
                v = (v > 20.f) ? v : log1pf(__expf(v));
            }
            C[(size_t)gm * ldc + gn] = v;
        }
    }
}

// ---------------- depthwise causal conv (k=4) + SiLU: xm (cols 0..8191 of xz) -> xt [B,LS,DINNER]
__global__ __launch_bounds__(256) void k_dwconv(
    const float* __restrict__ xz, const float* __restrict__ cw,
    const float* __restrict__ cb, float* __restrict__ xt)
{
    int idx = blockIdx.x * 256 + threadIdx.x;   // B*LS*DINNER
    int c = idx & (DINNER - 1);
    int rest = idx >> 13;
    int l = rest % LS;
    int b = rest / LS;
    float acc = cb[c];
#pragma unroll
    for (int k = 0; k < 4; ++k) {
        int t = l - 3 + k;
        if (t >= 0) acc += xz[((size_t)(b * LS + t)) * (2 * DINNER) + c] * cw[c * 4 + k];
    }
    xt[idx] = silu_f(acc);
}

// ---------------- selective scan, 16 lanes per (b,c); gating fused
__global__ __launch_bounds__(256) void k_scan(
    const float* __restrict__ delta, const float* __restrict__ xt,
    const float* __restrict__ xd, const float* __restrict__ a_log,
    const float* __restrict__ dpar, const float* __restrict__ xz,
    float* __restrict__ y)
{
    int gt = blockIdx.x * 256 + threadIdx.x;    // B*DINNER*16 = 262144
    int n = gt & 15;
    int c = (gt >> 4) & (DINNER - 1);
    int b = gt >> 17;
    float A = -__expf(a_log[c * 16 + n]);
    float dp = dpar[c];
    float h = 0.f;
    for (int t = 0; t < LS; ++t) {
        int base = b * LS + t;
        float d = delta[(size_t)base * DINNER + c];
        float xv = xt[(size_t)base * DINNER + c];
        float Bt = xd[(size_t)base * NX + DTRANK + n];
        float Ct = xd[(size_t)base * NX + DTRANK + DSTATE + n];
        h = __expf(d * A) * h + (d * xv) * Bt;
        float yp = h * Ct;
        yp += __shfl_xor(yp, 8, 16);
        yp += __shfl_xor(yp, 4, 16);
        yp += __shfl_xor(yp, 2, 16);
        yp += __shfl_xor(yp, 1, 16);
        if (n == 0) {
            float zv = xz[(size_t)base * (2 * DINNER) + DINNER + c];
            y[(size_t)base * DINNER + c] = (yp + xv * dp) * silu_f(zv);
        }
    }
}

// ---------------- residual add + transpose to [B,4096,255]
__global__ __launch_bounds__(256) void k_addres(
    const float* __restrict__ mo, const float* __restrict__ h, float* __restrict__ r)
{
    int idx = blockIdx.x * 256 + threadIdx.x;   // B*LS*C3
    int c = idx & (C3 - 1);
    int rest = idx >> 12;
    int l = rest % LS;
    int b = rest / LS;
    float v = mo[idx] + h[idx];
    r[((size_t)b * C3 + c) * LS + l] = v;
}

// ---------------- decoder convT1: [B,4096,255] -> [B,2048,512], s=2 p=2 k=8, +BN+ReLU
__global__ __launch_bounds__(512) void k_convt1(
    const float* __restrict__ in, const float* __restrict__ w,
    const float* __restrict__ bias, const float* __restrict__ g,
    const float* __restrict__ be, const float* __restrict__ rm,
    const float* __restrict__ rv, float* __restrict__ out)
{
    __shared__ float ws[512 * 8];
    int oc = blockIdx.x % 2048, b = blockIdx.x / 2048;
    int j = threadIdx.x;   // 0..511
    int lI[4]; float mk[4]; int kI[4];
#pragma unroll
    for (int u = 0; u < 4; ++u) {
        int k = (j & 1) + 2 * u;         // k == j (mod 2)
        int l = (j + 2 - k) >> 1;
        bool v = (j + 2 - k >= 0) && (l >= 0) && (l < LS);
        kI[u] = k; mk[u] = v ? 1.f : 0.f; lI[u] = v ? l : 0;
    }
    float acc = 0.f;
    const float* ib = in + (size_t)b * C3 * LS;
    for (int ic0 = 0; ic0 < C3; ic0 += 512) {
        __syncthreads();
        for (int i = j; i < 512 * 8; i += 512)
            ws[i] = w[((size_t)(ic0 + (i >> 3)) * 2048 + oc) * 8 + (i & 7)];
        __syncthreads();
        for (int icl = 0; icl < 512; ++icl) {
            const float* ip = ib + (size_t)(ic0 + icl) * LS;
            const float* wp = ws + icl * 8;
#pragma unroll
            for (int u = 0; u < 4; ++u) acc += mk[u] * ip[lI[u]] * wp[kI[u]];
        }
    }
    float s = g[oc] * rsqrtf(rv[oc] + 1e-5f);
    float o = (acc + bias[oc] - rm[oc]) * s + be[oc];
    out[((size_t)b * 2048 + oc) * 512 + j] = fmaxf(o, 0.f);
}

// ---------------- decoder convT2: [B,2048,512] -> [B,1024,2048], s=4 p=2 k=8, +BN+ReLU
__global__ __launch_bounds__(512) void k_convt2(
    const float* __restrict__ in, const float* __restrict__ w,
    const float* __restrict__ bias, const float* __restrict__ g,
    const float* __restrict__ be, const float* __restrict__ rm,
    const float* __restrict__ rv, float* __restrict__ out)
{
    __shared__ float ws[512 * 8];
    int oc = blockIdx.x % 1024, b = blockIdx.x / 1024;
    int tid = threadIdx.x;   // 0..511, 4 outputs each
    float acc[4] = {0, 0, 0, 0};
    int lA[4], lB[4], kA[4], kB[4]; float mA[4], mB[4];
#pragma unroll
    for (int u = 0; u < 4; ++u) {
        int j = tid + 512 * u;
        int q = (j + 2) & 3;
        int la = (j + 2 - q) >> 2;
        int lb = la - 1;
        kA[u] = q; kB[u] = q + 4;
        bool va = (la >= 0 && la < 512), vb = (lb >= 0 && lb < 512);
        mA[u] = va ? 1.f : 0.f; lA[u] = va ? la : 0;
        mB[u] = vb ? 1.f : 0.f; lB[u] = vb ? lb : 0;
    }
    const float* ib = in + (size_t)b * 2048 * 512;
    for (int ic0 = 0; ic0 < 2048; ic0 += 512) {
        __syncthreads();
        for (int i = tid; i < 512 * 8; i += 512)
            ws[i] = w[((size_t)(ic0 + (i >> 3)) * 1024 + oc) * 8 + (i & 7)];
        __syncthreads();
        for (int icl = 0; icl < 512; ++icl) {
            const float* ip = ib + (size_t)(ic0 + icl) * 512;
            const float* wp = ws + icl * 8;
#pragma unroll
            for (int u = 0; u < 4; ++u)
                acc[u] += mA[u] * ip[lA[u]] * wp[kA[u]] + mB[u] * ip[lB[u]] * wp[kB[u]];
        }
    }
    float s = g[oc] * rsqrtf(rv[oc] + 1e-5f);
#pragma unroll
    for (int u = 0; u < 4; ++u) {
        float o = (acc[u] + bias[oc] - rm[oc]) * s + be[oc];
        out[((size_t)b * 1024 + oc) * 2048 + tid + 512 * u] = fmaxf(o, 0.f);
    }
}

// ---------------- decoder convT3: [B,1024,2048] -> [B,8192], s=4 p=2 k=8, +bias -1
__global__ __launch_bounds__(256) void k_convt3(
    const float* __restrict__ in, const float* __restrict__ w,
    const float* __restrict__ b3, float* __restrict__ out)
{
    __shared__ float ws[1024 * 8];
    int tid = threadIdx.x;
    for (int i = tid; i < 8192; i += 256) ws[i] = w[i];
    __syncthreads();
    int b = blockIdx.x >> 5;
    int j = (blockIdx.x & 31) * 256 + tid;
    int q = (j + 2) & 3;
    int l1 = (j + 2 - q) >> 2;
    int l2 = l1 - 1;
    bool v1 = l1 < 2048, v2 = l2 >= 0;
    float acc = 0.f;
    const float* ib = in + (size_t)b * 1024 * 2048;
    for (int ic = 0; ic < 1024; ++ic) {
        const float* ip = ib + (size_t)ic * 2048;
        float x1 = v1 ? ip[l1] : 0.f;
        float x2 = v2 ? ip[l2] : 0.f;
        acc += x1 * ws[ic * 8 + q] + x2 * ws[ic * 8 + q + 4];
    }
    out[b * 8192 + j] = acc + b3[0] - 1.f;
}

} // namespace

extern "C" void kernel_launch(void* const* d_in, const int* in_sizes, int n_in,
                              void* d_out, int out_size, void* d_ws, size_t ws_size,
                              hipStream_t stream)
{
    const float* x    = (const float*)d_in[0];
    const float* ew1  = (const float*)d_in[1];
    const float* eb1  = (const float*)d_in[2];
    const float* eg1  = (const float*)d_in[3];
    const float* ebe1 = (const float*)d_in[4];
    const float* em1  = (const float*)d_in[5];
    const float* ev1  = (const float*)d_in[6];
    const float* ew2  = (const float*)d_in[7];
    const float* eb2  = (const float*)d_in[8];
    const float* eg2  = (const float*)d_in[9];
    const float* ebe2 = (const float*)d_in[10];
    const float* em2  = (const float*)d_in[11];
    const float* ev2  = (const float*)d_in[12];
    const float* ew3  = (const float*)d_in[13];
    const float* eb3  = (const float*)d_in[14];
    const float* eg3  = (const float*)d_in[15];
    const float* ebe3 = (const float*)d_in[16];
    const float* em3  = (const float*)d_in[17];
    const float* ev3  = (const float*)d_in[18];
    const float* norm_w = (const float*)d_in[19];
    const float* in_w   = (const float*)d_in[20];
    const float* cw     = (const float*)d_in[21];
    const float* cb     = (const float*)d_in[22];
    const float* xp_w   = (const float*)d_in[23];
    const float* dtp_w  = (const float*)d_in[24];
    const float* dtp_b  = (const float*)d_in[25];
    const float* a_log  = (const float*)d_in[26];
    const float* dpar   = (const float*)d_in[27];
    const float* out_w  = (const float*)d_in[28];
    const float* dw1  = (const float*)d_in[29];
    const float* db1  = (const float*)d_in[30];
    const float* dg1  = (const float*)d_in[31];
    const float* dbe1 = (const float*)d_in[32];
    const float* dm1  = (const float*)d_in[33];
    const float* dv1  = (const float*)d_in[34];
    const float* dw2  = (const float*)d_in[35];
    const float* db2  = (const float*)d_in[36];
    const float* dg2  = (const float*)d_in[37];
    const float* dbe2 = (const float*)d_in[38];
    const float* dm2  = (const float*)d_in[39];
    const float* dv2  = (const float*)d_in[40];
    const float* dw3  = (const float*)d_in[41];
    const float* db3  = (const float*)d_in[42];

    float* W = (float*)d_ws;
    size_t o_b1 = 0;                                    // [B,1024,2048] (reused for d2)
    size_t o_b2 = o_b1 + (size_t)Bsz * C1 * L1;         // [B,2048,512]  (reused for d1)
    size_t o_h  = o_b2 + (size_t)Bsz * C2 * L2;         // [B,255,4096] residual
    size_t o_hs = o_h  + (size_t)Bsz * LS * C3;         // [B,255,4096] rmsnorm out / mamba out reuse
    size_t o_xz = o_hs + (size_t)Bsz * LS * C3;         // [B,255,16384]
    size_t o_xt = o_xz + (size_t)Bsz * LS * 2 * DINNER; // [B,255,8192]
    size_t o_xd = o_xt + (size_t)Bsz * LS * DINNER;     // [B,255,288]
    size_t o_dl = o_xd + (size_t)Bsz * LS * NX;         // [B,255,8192]
    size_t o_y  = o_dl + (size_t)Bsz * LS * DINNER;     // [B,255,8192]
    size_t o_r  = o_y  + (size_t)Bsz * LS * DINNER;     // [B,4096,255]

    // encoder
    k_conv1<<<(Bsz * C1 * L1) / 256, 256, 0, stream>>>(x, ew1, eb1, eg1, ebe1, em1, ev1, W + o_b1);
    k_conv2<<<Bsz * C2, 512, 0, stream>>>(W + o_b1, ew2, eb2, eg2, ebe2, em2, ev2, W + o_b2);
    k_conv3<<<Bsz * C3, 256, 0, stream>>>(W + o_b2, ew3, eb3, eg3, ebe3, em3, ev3, W + o_h);

    // mamba
    k_rmsnorm<<<Bsz * LS, 256, 0, stream>>>(W + o_h, norm_w, W + o_hs);
    k_gemm_nt<0><<<dim3((2 * DINNER) / 64, (MROWS + 63) / 64), dim3(16, 16), 0, stream>>>(
        W + o_hs, C3, in_w, C3, W + o_xz, 2 * DINNER, MROWS, 2 * DINNER, C3, nullptr);
    k_dwconv<<<(Bsz * LS * DINNER) / 256, 256, 0, stream>>>(W + o_xz, cw, cb, W + o_xt);
    k_gemm_nt<0><<<dim3((NX + 63) / 64, (MROWS + 63) / 64), dim3(16, 16), 0, stream>>>(
        W + o_xt, DINNER, xp_w, DINNER, W + o_xd, NX, MROWS, NX, DINNER, nullptr);
    k_gemm_nt<1><<<dim3(DINNER / 64, (MROWS + 63) / 64), dim3(16, 16), 0, stream>>>(
        W + o_xd, NX, dtp_w, DTRANK, W + o_dl, DINNER, MROWS, DINNER, DTRANK, dtp_b);
    k_scan<<<(Bsz * DINNER * DSTATE) / 256, 256, 0, stream>>>(
        W + o_dl, W + o_xt, W + o_xd, a_log, dpar, W + o_xz, W + o_y);
    k_gemm_nt<0><<<dim3(C3 / 64, (MROWS + 63) / 64), dim3(16, 16), 0, stream>>>(
        W + o_y, DINNER, out_w, DINNER, W + o_hs, C3, MROWS, C3, DINNER, nullptr);
    k_addres<<<(Bsz * LS * C3) / 256, 256, 0, stream>>>(W + o_hs, W + o_h, W + o_r);

    // decoder (d1 reuses b2 slot, d2 reuses b1 slot)
    k_convt1<<<Bsz * 2048, 512, 0, stream>>>(W + o_r, dw1, db1, dg1, dbe1, dm1, dv1, W + o_b2);
    k_convt2<<<Bsz * 1024, 512, 0, stream>>>(W + o_b2, dw2, db2, dg2, dbe2, dm2, dv2, W + o_b1);
    k_convt3<<<Bsz * 32, 256, 0, stream>>>(W + o_b1, dw3, db3, (float*)d_out);
}